// Round 11
// baseline (241.827 us; speedup 1.0000x reference)
//
#include <hip/hip_runtime.h>

#define Nn 4096
#define Gd 512
#define Hd 256
#define PW 768   // packed operand width: 256 (Q or K) + 512 (normalized gene)

typedef float f32x4 __attribute__((ext_vector_type(4)));
typedef short s16x8 __attribute__((ext_vector_type(8)));
typedef _Float16 f16x8 __attribute__((ext_vector_type(8)));
typedef unsigned short u16x4v __attribute__((ext_vector_type(4)));
typedef unsigned short u16x8v __attribute__((ext_vector_type(8)));

// async global->LDS, 16B per lane; LDS dest must be wave-uniform base + lane*16.
#define GLL(gp, lp) __builtin_amdgcn_global_load_lds((const __attribute__((address_space(1))) void*)(gp), (__attribute__((address_space(3))) void*)(lp), 16, 0, 0)

// Fragment-tiled layout for MFMA operands: matrix [R rows][K cols] (bf16/u16)
// stored as 16x32 tiles; tile(TR,TK) of a matrix with NTK k-tiles lives at
// element offset ((TR*NTK)+TK)*512, and within the tile lane l's 8-elem frag
// (row=l&15, kseg=l>>4) is at l*8 -> one coalesced 1KB load per wave.
__device__ inline size_t tiled_off(int row, int col, int ntk) {
    return ((size_t)(row >> 4) * ntk + (col >> 5)) * 512
         + (size_t)((col & 31) >> 3) * 128 + (row & 15) * 8 + (col & 7);
}

// fp32 -> bf16 bits, round-to-nearest-even (integer path; no __bf16 types)
__device__ inline unsigned short f2bf(float x) {
    unsigned u = __builtin_bit_cast(unsigned, x);
    return (unsigned short)((u + 0x7FFFu + ((u >> 16) & 1u)) >> 16);
}
// fp32 -> fp16 bits
__device__ inline unsigned short f2h(float x) {
    return __builtin_bit_cast(unsigned short, (_Float16)x);
}

__device__ inline float tanh_fast(float x) {
    x = __builtin_fminf(__builtin_fmaxf(x, -15.f), 15.f);
    float e2 = __expf(2.f * x);
    return (e2 - 1.f) / (e2 + 1.f);
}

// ---------------------------------------------------------------- k_norm
__global__ __launch_bounds__(64) void k_norm(const float* __restrict__ gene,
                                             const float* __restrict__ pos,
                                             float* __restrict__ rinvb,
                                             float* __restrict__ sqbuf) {
    int i = blockIdx.x, t = threadIdx.x;
    const float4* gr = (const float4*)(gene + (size_t)i * Gd);
    float4 a = gr[t], b = gr[t + 64];
    float ss = a.x*a.x + a.y*a.y + a.z*a.z + a.w*a.w
             + b.x*b.x + b.y*b.y + b.z*b.z + b.w*b.w;
    #pragma unroll
    for (int m = 1; m < 64; m <<= 1) ss += __shfl_xor(ss, m, 64);
    if (t == 0) {
        rinvb[i] = 1.f / __builtin_fmaxf(__builtin_sqrtf(ss), 1e-12f);
        float p0 = pos[2*i], p1 = pos[2*i+1];
        sqbuf[i] = p0*p0 + p1*p1;
    }
}

// ---------------------------------------------------------------- k_wt
// Wt[768][512] fp16: rows 0-255 = Wq^T, 256-511 = Wk^T, 512-767 = Wv^T.
__global__ __launch_bounds__(256) void k_wt(const float* __restrict__ Wq,
                                            const float* __restrict__ Wk,
                                            const float* __restrict__ Wv,
                                            unsigned short* __restrict__ Wt) {
    __shared__ float tile[64][65];
    int t = threadIdx.x;
    int kb = blockIdx.x * 64;
    int by = blockIdx.y;
    int mid = by >> 2;
    int cb2 = (by & 3) * 64;
    const float* W = (mid == 0) ? Wq : (mid == 1) ? Wk : Wv;
    #pragma unroll
    for (int q = 0; q < 16; ++q) {
        int idx = q * 256 + t;
        int row = idx >> 6, col = idx & 63;
        tile[row][col] = W[(size_t)(kb + row) * Hd + cb2 + col];
    }
    __syncthreads();
    int crow = by * 64;
    #pragma unroll
    for (int q = 0; q < 16; ++q) {
        int idx = q * 256 + t;
        int c = idx >> 6, k = idx & 63;
        Wt[(size_t)(crow + c) * Gd + kb + k] = f2h(tile[k][c]);
    }
}

// ---------------------------------------------------------------- k_wt2
__global__ __launch_bounds__(256) void k_wt2(const float* __restrict__ W1,
                                             const float* __restrict__ W2,
                                             unsigned short* __restrict__ W1t,
                                             unsigned short* __restrict__ W2t) {
    __shared__ float tile[64][65];
    int t = threadIdx.x;
    int kb = blockIdx.x * 64;
    int by = blockIdx.y;
    int mid = by >> 2;
    int cb2 = (by & 3) * 64;
    const float* W = (mid == 0) ? W1 : W2;
    unsigned short* Wo = (mid == 0) ? W1t : W2t;
    #pragma unroll
    for (int q = 0; q < 16; ++q) {
        int idx = q * 256 + t;
        int row = idx >> 6, col = idx & 63;
        tile[row][col] = W[(size_t)(kb + row) * Hd + cb2 + col];
    }
    __syncthreads();
    #pragma unroll
    for (int q = 0; q < 16; ++q) {
        int idx = q * 256 + t;
        int c = idx >> 6, k = idx & 63;
        Wo[(size_t)(cb2 + c) * Hd + kb + k] = f2h(tile[k][c]);
    }
}

// ---------------------------------------------------------------- k_mlp_mfma
__global__ __launch_bounds__(256) void k_mlp_mfma(const float* __restrict__ pos,
                                                  const float* __restrict__ Ws, const float* __restrict__ bs,
                                                  const unsigned short* __restrict__ W1t, const float* __restrict__ b1,
                                                  const unsigned short* __restrict__ W2t, const float* __restrict__ b2,
                                                  const float* __restrict__ Wf, const float* __restrict__ bf,
                                                  float* __restrict__ fbuf,
                                                  float* __restrict__ ebuf) {
    __shared__ unsigned short A_lds[16 * 256];
    __shared__ unsigned short H_lds[16 * 256];
    __shared__ unsigned short Bs_[256 * 32];
    __shared__ float E_lds[16][256];
    __shared__ float sp_[32];
    int t = threadIdx.x;
    int w = t >> 6, l = t & 63;
    int rb = blockIdx.x * 16;
    if (t < 32) sp_[t] = pos[rb * 2 + t];
    __syncthreads();
    #pragma unroll
    for (int q = 0; q < 16; ++q) {
        float v = sp_[2*q] * Ws[t] + sp_[2*q+1] * Ws[Hd + t] + bs[t];
        A_lds[q * 256 + t] = f2h(v);
    }
    __syncthreads();

    f32x4 acc[4] = {};
    for (int kt = 0; kt < Hd; kt += 32) {
        #pragma unroll
        for (int q = 0; q < 4; ++q) {
            int e = q * 256 + t;
            int row = e >> 2, seg = e & 3;
            GLL(W1t + (size_t)row * Hd + kt + seg * 8, &Bs_[e * 8]);
        }
        __syncthreads();
        f16x8 af = *(const f16x8*)&A_lds[(l & 15) * 256 + kt + (l >> 4) * 8];
        #pragma unroll
        for (int nf = 0; nf < 4; ++nf) {
            f16x8 bb = *(const f16x8*)&Bs_[(w * 64 + nf * 16 + (l & 15)) * 32 + (l >> 4) * 8];
            acc[nf] = __builtin_amdgcn_mfma_f32_16x16x32_f16(af, bb, acc[nf], 0, 0, 0);
        }
        __syncthreads();
    }
    #pragma unroll
    for (int nf = 0; nf < 4; ++nf) {
        int c = w * 64 + nf * 16 + (l & 15);
        float bb = b1[c];
        #pragma unroll
        for (int v = 0; v < 4; ++v) {
            int r = ((l >> 4) << 2) + v;
            H_lds[r * 256 + c] = f2h(tanh_fast(acc[nf][v] + bb));
        }
    }
    __syncthreads();

    f32x4 acc2[4] = {};
    for (int kt = 0; kt < Hd; kt += 32) {
        #pragma unroll
        for (int q = 0; q < 4; ++q) {
            int e = q * 256 + t;
            int row = e >> 2, seg = e & 3;
            GLL(W2t + (size_t)row * Hd + kt + seg * 8, &Bs_[e * 8]);
        }
        __syncthreads();
        f16x8 af = *(const f16x8*)&H_lds[(l & 15) * 256 + kt + (l >> 4) * 8];
        #pragma unroll
        for (int nf = 0; nf < 4; ++nf) {
            f16x8 bb = *(const f16x8*)&Bs_[(w * 64 + nf * 16 + (l & 15)) * 32 + (l >> 4) * 8];
            acc2[nf] = __builtin_amdgcn_mfma_f32_16x16x32_f16(af, bb, acc2[nf], 0, 0, 0);
        }
        __syncthreads();
    }
    #pragma unroll
    for (int nf = 0; nf < 4; ++nf) {
        int c = w * 64 + nf * 16 + (l & 15);
        float bb = b2[c];
        #pragma unroll
        for (int v = 0; v < 4; ++v)
            E_lds[((l >> 4) << 2) + v][c] = __builtin_fmaxf(acc2[nf][v] + bb, 0.f);
    }
    __syncthreads();

    f32x4 wf4 = *(const f32x4*)&Wf[l * 4];
    #pragma unroll
    for (int rr = 0; rr < 4; ++rr) {
        int r = w * 4 + rr;
        f32x4 ev = *(const f32x4*)&E_lds[r][l * 4];
        float s = ev[0]*wf4[0] + ev[1]*wf4[1] + ev[2]*wf4[2] + ev[3]*wf4[3];
        #pragma unroll
        for (int m = 1; m < 64; m <<= 1) s += __shfl_xor(s, m, 64);
        if (l == 0) {
            float fv = s + bf[0];
            fbuf[rb + r] = fv;
            float fc = __builtin_fminf(__builtin_fmaxf(fv, -15.f), 15.f);
            ebuf[rb + r] = __expf(2.f * fc);   // tanh(fi-fj)=(Ei-Ej)/(Ei+Ej)
        }
    }
}

// ---------------------------------------------------------------- k_pack
// normalized gene (bf16) into tiled cols [256,768) of packA/packB; fp16 gene.
__global__ __launch_bounds__(256) void k_pack(const float* __restrict__ gene,
                                              const float* __restrict__ rinvb,
                                              unsigned short* __restrict__ packA,
                                              unsigned short* __restrict__ packB,
                                              unsigned short* __restrict__ geneh) {
    int id = blockIdx.x * 256 + threadIdx.x;
    int row = id >> 7;
    int c4 = (id & 127) << 2;
    float ri = rinvb[row];
    float4 v = *(const float4*)(gene + (size_t)row * Gd + c4);
    u16x4v h;
    h[0] = f2h(v.x); h[1] = f2h(v.y); h[2] = f2h(v.z); h[3] = f2h(v.w);
    *(u16x4v*)(geneh + (size_t)row * Gd + c4) = h;
    u16x4v b;
    b[0] = f2bf(v.x * ri); b[1] = f2bf(v.y * ri);
    b[2] = f2bf(v.z * ri); b[3] = f2bf(v.w * ri);
    size_t off = tiled_off(row, Hd + c4, PW / 32);   // (cp&7) in {0,4}: 4 contiguous
    *(u16x4v*)(packA + off) = b;
    *(u16x4v*)(packB + off) = b;
}

// ---------------------------------------------------------------- k_qkv_mfma
// C[4096][768] = geneh @ Wt^T (fp16 MFMA). Outputs in fragment-tiled layout.
__global__ __launch_bounds__(256) void k_qkv_mfma(const unsigned short* __restrict__ geneh,
                                                  const unsigned short* __restrict__ Wt,
                                                  const float* __restrict__ bq,
                                                  const float* __restrict__ bk,
                                                  const float* __restrict__ bv,
                                                  unsigned short* __restrict__ packA,
                                                  unsigned short* __restrict__ packB,
                                                  unsigned short* __restrict__ Vt) {
    __shared__ unsigned short As[64 * 32];
    __shared__ unsigned short Bs[128 * 32];
    int t = threadIdx.x;
    int w = t >> 6, l = t & 63;
    int wm = (w >> 1) * 32, wn = (w & 1) * 64;
    int rb = blockIdx.x * 64;
    int cb = blockIdx.y * 128;
    int mid = blockIdx.y >> 1;
    const float* bia = (mid == 0) ? bq : (mid == 1) ? bk : bv;

    f32x4 acc[2][4] = {};

    for (int kt = 0; kt < Gd; kt += 32) {
        {
            int row = t >> 2, seg = t & 3;
            GLL(geneh + (size_t)(rb + row) * Gd + kt + seg * 8, &As[t * 8]);
        }
        #pragma unroll
        for (int q = 0; q < 2; ++q) {
            int e = q * 256 + t;
            int row = e >> 2, seg = e & 3;
            GLL(Wt + (size_t)(cb + row) * Gd + kt + seg * 8, &Bs[e * 8]);
        }
        __syncthreads();
        f16x8 af[2], bfr[4];
        #pragma unroll
        for (int mf = 0; mf < 2; ++mf)
            af[mf] = *(const f16x8*)&As[(wm + mf * 16 + (l & 15)) * 32 + (l >> 4) * 8];
        #pragma unroll
        for (int nf = 0; nf < 4; ++nf)
            bfr[nf] = *(const f16x8*)&Bs[(wn + nf * 16 + (l & 15)) * 32 + (l >> 4) * 8];
        #pragma unroll
        for (int mf = 0; mf < 2; ++mf)
            #pragma unroll
            for (int nf = 0; nf < 4; ++nf)
                acc[mf][nf] = __builtin_amdgcn_mfma_f32_16x16x32_f16(af[mf], bfr[nf], acc[mf][nf], 0, 0, 0);
        __syncthreads();
    }

    float scale = (mid == 0) ? 0.0625f : 1.f;
    #pragma unroll
    for (int nf = 0; nf < 4; ++nf) {
        int cg = cb + wn + nf * 16 + (l & 15);
        int cloc = cg - mid * 256;
        float bb = bia[cloc];
        #pragma unroll
        for (int mf = 0; mf < 2; ++mf) {
            int r0 = rb + wm + mf * 16 + ((l >> 4) << 2);
            if (mid == 2) {
                // Vt tiled [256 rows=cols of V][4096 k=nodes], NTK=128
                u16x4v o;
                #pragma unroll
                for (int v = 0; v < 4; ++v) o[v] = f2bf(acc[mf][nf][v] + bb);
                *(u16x4v*)(Vt + tiled_off(cloc, r0, Nn / 32)) = o;  // r0&7 in {0,4}
            } else {
                unsigned short* dst = (mid == 0) ? packA : packB;
                #pragma unroll
                for (int v = 0; v < 4; ++v)
                    dst[tiled_off(r0 + v, cloc, PW / 32)] = f2bf((acc[mf][nf][v] + bb) * scale);
            }
        }
    }
}

// ---------------------------------------------------------------- k_logits
// Fragment-tiled operands read register-direct from global: NO LDS, NO
// barriers in the K loop. Swapped-operand MFMA (lane holds 4 consecutive
// S-cols). Epilogue: gaussian (joint exp) + tanh via precomputed E=e^{2f};
// fused per-64-col partial max/sumexp.
__global__ __launch_bounds__(256) void k_logits(const unsigned short* __restrict__ packA,
                                                const unsigned short* __restrict__ packB,
                                                const float* __restrict__ pos,
                                                const float* __restrict__ ebuf,
                                                const float* __restrict__ sqbuf,
                                                float* __restrict__ S,
                                                float* __restrict__ pmaxb,
                                                float* __restrict__ psumb) {
    int t = threadIdx.x;
    int w = t >> 6, l = t & 63;
    int wr = (w >> 1) * 64, wc = (w & 1) * 64;
    int rb = blockIdx.x * 128, cb = blockIdx.y * 128;
    const int NTK = PW / 32;   // 24
    const unsigned short* baseA = packA + ((size_t)((rb >> 4) + (w >> 1) * 4) * NTK) * 512 + l * 8;
    const unsigned short* baseB = packB + ((size_t)((cb >> 4) + (w & 1) * 4) * NTK) * 512 + l * 8;

    f32x4 acc[4][4] = {};   // [cf][rf]

    for (int kt = 0; kt < NTK; ++kt) {
        s16x8 af[4], bfr[4];
        #pragma unroll
        for (int rf = 0; rf < 4; ++rf)
            af[rf] = *(const s16x8*)(baseA + ((size_t)rf * NTK + kt) * 512);
        #pragma unroll
        for (int cf = 0; cf < 4; ++cf)
            bfr[cf] = *(const s16x8*)(baseB + ((size_t)cf * NTK + kt) * 512);
        #pragma unroll
        for (int cf = 0; cf < 4; ++cf)
            #pragma unroll
            for (int rf = 0; rf < 4; ++rf)
                acc[cf][rf] = __builtin_amdgcn_mfma_f32_16x16x32_bf16(bfr[cf], af[rf], acc[cf][rf], 0, 0, 0);
    }

    // epilogue: D-col (l&15) = S-row, D-row ((l>>4)*4+v) = S-col
    int lv = (l >> 4) << 2;
    #pragma unroll
    for (int rf = 0; rf < 4; ++rf) {
        int r = rb + wr + rf * 16 + (l & 15);
        float Ei = ebuf[r], sqi = sqbuf[r];
        float pi0 = pos[2*r], pi1 = pos[2*r+1];
        f32x4 outs[4];
        #pragma unroll
        for (int cf = 0; cf < 4; ++cf) {
            int c0 = cb + wc + cf * 16 + lv;
            f32x4 Ej  = *(const f32x4*)(ebuf + c0);
            f32x4 sqj = *(const f32x4*)(sqbuf + c0);
            f32x4 p01 = *(const f32x4*)(pos + 2 * c0);
            f32x4 p23 = *(const f32x4*)(pos + 2 * c0 + 4);
            float pj0[4] = {p01[0], p01[2], p23[0], p23[2]};
            float pj1[4] = {p01[1], p01[3], p23[1], p23[3]};
            f32x4 o;
            #pragma unroll
            for (int v = 0; v < 4; ++v) {
                float d2 = __builtin_fmaxf(sqi + sqj[v] - 2.f * (pi0 * pj0[v] + pi1 * pj1[v]), 0.f);
                float th = (Ei - Ej[v]) / (Ei + Ej[v]);
                o[v] = acc[cf][rf][v] + __expf(-0.5f * d2) + th;
            }
            outs[cf] = o;
            *(f32x4*)(S + (size_t)r * Nn + c0) = o;
        }
        float mx = -3.4e38f;
        #pragma unroll
        for (int cf = 0; cf < 4; ++cf)
            #pragma unroll
            for (int v = 0; v < 4; ++v) mx = __builtin_fmaxf(mx, outs[cf][v]);
        mx = __builtin_fmaxf(mx, __shfl_xor(mx, 16));
        mx = __builtin_fmaxf(mx, __shfl_xor(mx, 32));
        float s = 0.f;
        #pragma unroll
        for (int cf = 0; cf < 4; ++cf)
            #pragma unroll
            for (int v = 0; v < 4; ++v) s += __expf(outs[cf][v] - mx);
        s += __shfl_xor(s, 16);
        s += __shfl_xor(s, 32);
        if (l < 16) {
            int chunk = blockIdx.y * 2 + (w & 1);
            pmaxb[(size_t)r * 64 + chunk] = mx;
            psumb[(size_t)r * 64 + chunk] = s;
        }
    }
}

// ---------------------------------------------------------------- k_rowstats2
__global__ __launch_bounds__(256) void k_rowstats2(const float* __restrict__ pmaxb,
                                                   const float* __restrict__ psumb,
                                                   float* __restrict__ mbuf,
                                                   float* __restrict__ lbuf) {
    int r = blockIdx.x * 256 + threadIdx.x;
    const f32x4* pm = (const f32x4*)(pmaxb + (size_t)r * 64);
    const f32x4* ps = (const f32x4*)(psumb + (size_t)r * 64);
    float m = -3.4e38f;
    #pragma unroll
    for (int i = 0; i < 16; ++i) {
        f32x4 v = pm[i];
        m = __builtin_fmaxf(m, __builtin_fmaxf(__builtin_fmaxf(v[0], v[1]),
                                               __builtin_fmaxf(v[2], v[3])));
    }
    float s = 0.f;
    #pragma unroll
    for (int i = 0; i < 16; ++i) {
        f32x4 v = pm[i], u = ps[i];
        s += u[0] * __expf(v[0] - m) + u[1] * __expf(v[1] - m)
           + u[2] * __expf(v[2] - m) + u[3] * __expf(v[3] - m);
    }
    mbuf[r] = m;
    lbuf[r] = 1.f / s;
}

// ---------------------------------------------------------------- k_out
// 32-row tiles, 4 k-chunks. V fragments register-direct from tiled Vt;
// only the 32x32 S->bf16 A-tile goes through LDS.
__global__ __launch_bounds__(256) void k_out(float* __restrict__ S,
                                             const unsigned short* __restrict__ Vt,
                                             const float* __restrict__ mbuf,
                                             const float* __restrict__ lbuf,
                                             float* __restrict__ Opart) {
    __shared__ unsigned short As[32 * 32];
    __shared__ float sm[32], sl[32];
    int t = threadIdx.x;
    int w = t >> 6, l = t & 63;
    int rb = blockIdx.x * 32;
    int k0 = blockIdx.y * 1024;
    if (t < 32) { sm[t] = mbuf[rb + t]; sl[t] = lbuf[rb + t]; }
    __syncthreads();

    const unsigned short* baseV = Vt + ((size_t)(w * 4) * (Nn / 32)) * 512 + l * 8;

    f32x4 acc[2][4] = {};

    for (int kt = 0; kt < 1024; kt += 32) {
        int TK = (k0 + kt) >> 5;
        {
            int row = t >> 3, seg = t & 7;
            size_t off = (size_t)(rb + row) * Nn + k0 + kt + seg * 4;
            float4 x = *(const float4*)(S + off);
            float m = sm[row], lv2 = sl[row];
            x.x = __expf(x.x - m) * lv2;
            x.y = __expf(x.y - m) * lv2;
            x.z = __expf(x.z - m) * lv2;
            x.w = __expf(x.w - m) * lv2;
            *(float4*)(S + off) = x;
            u16x4v b;
            b[0] = f2bf(x.x); b[1] = f2bf(x.y); b[2] = f2bf(x.z); b[3] = f2bf(x.w);
            *(u16x4v*)&As[row * 32 + seg * 4] = b;
        }
        __syncthreads();
        s16x8 a[2], bfr[4];
        #pragma unroll
        for (int mf = 0; mf < 2; ++mf)
            a[mf] = *(const s16x8*)&As[(mf * 16 + (l & 15)) * 32 + (l >> 4) * 8];
        #pragma unroll
        for (int nf = 0; nf < 4; ++nf)
            bfr[nf] = *(const s16x8*)(baseV + ((size_t)nf * (Nn / 32) + TK) * 512);
        #pragma unroll
        for (int nf = 0; nf < 4; ++nf)
            #pragma unroll
            for (int mf = 0; mf < 2; ++mf)
                acc[mf][nf] = __builtin_amdgcn_mfma_f32_16x16x32_bf16(a[mf], bfr[nf], acc[mf][nf], 0, 0, 0);
        __syncthreads();
    }
    float* dst = Opart + (size_t)blockIdx.y * Nn * Hd;
    #pragma unroll
    for (int mf = 0; mf < 2; ++mf)
        #pragma unroll
        for (int v = 0; v < 4; ++v) {
            int r = rb + mf * 16 + ((l >> 4) << 2) + v;
            #pragma unroll
            for (int nf = 0; nf < 4; ++nf) {
                int c = w * 64 + nf * 16 + (l & 15);
                dst[(size_t)r * Hd + c] = acc[mf][nf][v];
            }
        }
}

// ---------------------------------------------------------------- k_reduce
__global__ __launch_bounds__(256) void k_reduce(const float* __restrict__ P,
                                                float* __restrict__ O) {
    int id = blockIdx.x * 256 + threadIdx.x;
    size_t off = (size_t)id * 4;
    const size_t C = (size_t)Nn * Hd;
    float4 a = *(const float4*)(P + off);
    float4 b = *(const float4*)(P + C + off);
    float4 c = *(const float4*)(P + 2 * C + off);
    float4 d = *(const float4*)(P + 3 * C + off);
    float4 o;
    o.x = a.x + b.x + c.x + d.x;
    o.y = a.y + b.y + c.y + d.y;
    o.z = a.z + b.z + c.z + d.z;
    o.w = a.w + b.w + c.w + d.w;
    *(float4*)(O + off) = o;
}

// ---------------------------------------------------------------- launch
extern "C" void kernel_launch(void* const* d_in, const int* in_sizes, int n_in,
                              void* d_out, int out_size, void* d_ws, size_t ws_size,
                              hipStream_t stream) {
    const float* gene = (const float*)d_in[0];
    const float* pos  = (const float*)d_in[1];
    const float* Wq = (const float*)d_in[2];  const float* bq = (const float*)d_in[3];
    const float* Wk = (const float*)d_in[4];  const float* bk = (const float*)d_in[5];
    const float* Wv = (const float*)d_in[6];  const float* bv = (const float*)d_in[7];
    const float* Ws = (const float*)d_in[8];  const float* bs = (const float*)d_in[9];
    const float* W1 = (const float*)d_in[10]; const float* b1 = (const float*)d_in[11];
    const float* W2 = (const float*)d_in[12]; const float* b2 = (const float*)d_in[13];
    const float* Wf = (const float*)d_in[14]; const float* bf = (const float*)d_in[15];

    char* w8 = (char*)d_ws;
    // bytes: Vt [0,2M) | smalls [2M,2.125M) | packA [2.125M,8.4M) | packB
    // [8.4M,14.8M) | geneh [14.8M,19M) | Wt [19M,19.79M) | W1t/W2t [19.79M,20.05M)
    // pmax/psum (2MB) alias geneh (dead after k_qkv_mfma);
    // Opart (16.77MB) aliases packA+packB+geneh (all dead by k_out).
    unsigned short* Vt    = (unsigned short*)w8;                      // tiled [256][4096]
    float*  fbuf  = (float*)(w8 + 2097152);
    float*  sqbuf = fbuf + Nn;
    float*  rinvb = sqbuf + Nn;
    float*  mbuf  = rinvb + Nn;
    float*  lbuf  = mbuf + Nn;
    float*  ebuf  = lbuf + Nn;
    unsigned short* packA = (unsigned short*)(w8 + 2228224);          // tiled [4096][768]
    unsigned short* packB = (unsigned short*)(w8 + 8519680);          // tiled [4096][768]
    unsigned short* geneh = (unsigned short*)(w8 + 14811136);         // [4096][512]
    unsigned short* Wt    = (unsigned short*)(w8 + 19005440);         // [768][512]
    unsigned short* W1t   = (unsigned short*)(w8 + 19791872);         // [256][256]
    unsigned short* W2t   = (unsigned short*)(w8 + 19922944);         // [256][256]
    float*  pmaxb = (float*)(w8 + 14811136);                          // [4096][64]
    float*  psumb = (float*)(w8 + 14811136 + 1048576);                // [4096][64]
    float*  Opart = (float*)(w8 + 2228224);                           // [4][4096][256]

    float* S = (float*)d_out;                      // [N][N] attention weights
    float* O = S + (size_t)Nn * Nn;                // [N][256]

    k_norm<<<Nn, 64, 0, stream>>>(gene, pos, rinvb, sqbuf);
    k_wt<<<dim3(Gd / 64, PW / 64), 256, 0, stream>>>(Wq, Wk, Wv, Wt);
    k_wt2<<<dim3(Hd / 64, 8), 256, 0, stream>>>(W1, W2, W1t, W2t);
    k_mlp_mfma<<<Nn / 16, 256, 0, stream>>>(pos, Ws, bs, W1t, b1, W2t, b2, Wf, bf,
                                            fbuf, ebuf);
    k_pack<<<(Nn * (Gd / 4)) / 256, 256, 0, stream>>>(gene, rinvb, packA, packB, geneh);
    k_qkv_mfma<<<dim3(Nn / 64, 6), 256, 0, stream>>>(geneh, Wt, bq, bk, bv,
                                                     packA, packB, Vt);
    k_logits<<<dim3(Nn / 128, Nn / 128), 256, 0, stream>>>(packA, packB, pos,
                                                           ebuf, sqbuf, S, pmaxb, psumb);
    k_rowstats2<<<Nn / 256, 256, 0, stream>>>(pmaxb, psumb, mbuf, lbuf);
    k_out<<<dim3(Nn / 32, 4), 256, 0, stream>>>(S, Vt, mbuf, lbuf, Opart);
    k_reduce<<<(Nn * Hd / 4) / 256, 256, 0, stream>>>(Opart, O);
}